// Round 1
// baseline (891.412 us; speedup 1.0000x reference)
//
#include <hip/hip_runtime.h>

#define Hn 1024
#define Dn 256
#define Bn 8
#define NWG 72
#define DTf 0.125f

__constant__ float cA[6][5] = {
  {0.f,0.f,0.f,0.f,0.f},
  {1.0f/5.0f,0.f,0.f,0.f,0.f},
  {3.0f/40.0f, 9.0f/40.0f,0.f,0.f,0.f},
  {44.0f/45.0f, -56.0f/15.0f, 32.0f/9.0f,0.f,0.f},
  {19372.0f/6561.0f, -25360.0f/2187.0f, 64448.0f/6561.0f, -212.0f/729.0f,0.f},
  {9017.0f/3168.0f, -355.0f/33.0f, 46732.0f/5247.0f, 49.0f/176.0f, -5103.0f/18656.0f}
};
__constant__ float cCc[6] = {0.f, 0.2f, 0.3f, 0.8f, 8.0f/9.0f, 1.0f};
__constant__ float cBW[6] = {35.0f/384.0f, 0.f, 500.0f/1113.0f, 125.0f/192.0f,
                             -2187.0f/6784.0f, 11.0f/84.0f};

// ---------------- precompute M = (W1^T W1) .* (W2 W2^T) ----------------
__global__ __launch_bounds__(256) void precomp_M(const float* __restrict__ W1,
                                                 const float* __restrict__ W2,
                                                 float* __restrict__ Mm) {
  __shared__ float a1k[32][64];
  __shared__ float a1l[32][64];
  __shared__ float w2kT[32][72];  // [d][k], padded
  __shared__ float w2lT[32][72];
  const int tid = threadIdx.x;
  const int k0 = (blockIdx.x & 15) * 64;
  const int l0 = (blockIdx.x >> 4) * 64;
  const int kq = tid & 15, lq = tid >> 4;
  float g1[4][4] = {}, g2[4][4] = {};
  for (int dc = 0; dc < 8; dc++) {
    const int d0 = dc * 32;
    __syncthreads();
    for (int idx = tid; idx < 2048; idx += 256) {
      const int r1 = idx >> 6, c1 = idx & 63;           // r1: 0..31
      a1k[r1][c1] = W1[(d0 + r1) * Hn + k0 + c1];
      a1l[r1][c1] = W1[(d0 + r1) * Hn + l0 + c1];
    }
    for (int idx = tid; idx < 2048; idx += 256) {
      const int r1 = idx >> 5, c1 = idx & 31;           // r1: k/l idx 0..63, c1: d 0..31
      w2kT[c1][r1] = W2[(k0 + r1) * Dn + d0 + c1];
      w2lT[c1][r1] = W2[(l0 + r1) * Dn + d0 + c1];
    }
    __syncthreads();
    #pragma unroll 4
    for (int dd = 0; dd < 32; dd++) {
      const float4 ak = *(const float4*)&a1k[dd][kq * 4];
      const float4 al = *(const float4*)&a1l[dd][lq * 4];
      const float4 wk = *(const float4*)&w2kT[dd][kq * 4];
      const float4 wl = *(const float4*)&w2lT[dd][lq * 4];
      const float akv[4] = {ak.x, ak.y, ak.z, ak.w};
      const float alv[4] = {al.x, al.y, al.z, al.w};
      const float wkv[4] = {wk.x, wk.y, wk.z, wk.w};
      const float wlv[4] = {wl.x, wl.y, wl.z, wl.w};
      #pragma unroll
      for (int i = 0; i < 4; i++)
        #pragma unroll
        for (int j = 0; j < 4; j++) {
          g1[i][j] += akv[i] * alv[j];
          g2[i][j] += wkv[i] * wlv[j];
        }
    }
  }
  #pragma unroll
  for (int i = 0; i < 4; i++)
    #pragma unroll
    for (int j = 0; j < 4; j++)
      Mm[(k0 + kq * 4 + i) * Hn + l0 + lq * 4 + j] = g1[i][j] * g2[i][j];
}

// ---------------- precompute Z = W2 @ W1 (H x H) ----------------
__global__ __launch_bounds__(256) void precomp_Z(const float* __restrict__ W1,
                                                 const float* __restrict__ W2,
                                                 float* __restrict__ Zz) {
  __shared__ float w2lT[64][72];  // [d][l]
  __shared__ float w1t[64][64];   // [d][e]
  const int tid = threadIdx.x;
  const int e0 = (blockIdx.x & 15) * 64;
  const int l0 = (blockIdx.x >> 4) * 64;
  const int eq = tid & 15, lq = tid >> 4;
  float acc[4][4] = {};
  for (int dc = 0; dc < 4; dc++) {
    const int d0 = dc * 64;
    __syncthreads();
    for (int idx = tid; idx < 4096; idx += 256) {
      const int r1 = idx >> 6, c1 = idx & 63;
      w2lT[c1][r1] = W2[(l0 + r1) * Dn + d0 + c1];
      w1t[r1][c1] = W1[(d0 + r1) * Hn + e0 + c1];
    }
    __syncthreads();
    #pragma unroll 4
    for (int dd = 0; dd < 64; dd++) {
      const float4 wv = *(const float4*)&w2lT[dd][lq * 4];
      const float4 xv = *(const float4*)&w1t[dd][eq * 4];
      const float wvv[4] = {wv.x, wv.y, wv.z, wv.w};
      const float xvv[4] = {xv.x, xv.y, xv.z, xv.w};
      #pragma unroll
      for (int i = 0; i < 4; i++)
        #pragma unroll
        for (int j = 0; j < 4; j++)
          acc[i][j] += wvv[i] * xvv[j];
    }
  }
  #pragma unroll
  for (int i = 0; i < 4; i++)
    #pragma unroll
    for (int j = 0; j < 4; j++)
      Zz[(l0 + lq * 4 + i) * Hn + e0 + eq * 4 + j] = acc[i][j];
}

// ---------------- precompute small: c, bz, ux0, inits ----------------
__global__ __launch_bounds__(256) void precomp_small(
    const float* __restrict__ x0, const float* __restrict__ W1,
    const float* __restrict__ W2, const float* __restrict__ b2,
    float* __restrict__ cc, float* __restrict__ bz, float* __restrict__ ux,
    float* __restrict__ xcur, float* __restrict__ gk, float* __restrict__ kvec,
    float* __restrict__ scal, unsigned* __restrict__ bar) {
  const int wg = blockIdx.x, tid = threadIdx.x;
  if (wg < 32) {                 // ux[1] = x0 @ W1
    const int idx = wg * 256 + tid;
    const int b = idx >> 10, e = idx & 1023;
    float s = 0.f;
    for (int d = 0; d < Dn; d++) s += x0[b * Dn + d] * W1[d * Hn + e];
    ux[(1 * Bn + b) * Hn + e] = s;
  } else if (wg < 40) {          // zero gk parity 1
    for (int idx = (wg - 32) * 256 + tid; idx < 49152; idx += 8 * 256)
      gk[49152 + idx] = 0.f;
  } else if (wg < 42) {          // zero kvec parity 1
    for (int idx = (wg - 40) * 256 + tid; idx < 12288; idx += 2 * 256)
      kvec[12288 + idx] = 0.f;
  } else if (wg == 42) {         // xcur[1] = x0, scal = 0, bar = 0
    for (int idx = tid; idx < Bn * Dn; idx += 256) xcur[Bn * Dn + idx] = x0[idx];
    if (tid < 32) scal[tid] = 0.f;
    if (tid < 2) bar[tid] = 0u;
  } else if (wg < 47) {          // c[k] = W1[:,k] . W2[k,:]
    const int k = (wg - 43) * 256 + tid;
    float s = 0.f;
    for (int d = 0; d < Dn; d++) s += W1[d * Hn + k] * W2[k * Dn + d];
    cc[k] = s;
  } else {                       // bz[e] = b2 @ W1
    const int e = (wg - 47) * 256 + tid;
    float s = 0.f;
    for (int d = 0; d < Dn; d++) s += b2[d] * W1[d * Hn + e];
    bz[e] = s;
  }
}

// ---------------- grid barrier ----------------
__device__ __forceinline__ void gridbar(unsigned* cnt, unsigned* gen) {
  __syncthreads();
  if (threadIdx.x == 0) {
    __threadfence();
    const unsigned g = __hip_atomic_load(gen, __ATOMIC_RELAXED, __HIP_MEMORY_SCOPE_AGENT);
    const unsigned a = __hip_atomic_fetch_add(cnt, 1u, __ATOMIC_ACQ_REL, __HIP_MEMORY_SCOPE_AGENT);
    if (a == NWG - 1u) {
      __hip_atomic_store(cnt, 0u, __ATOMIC_RELAXED, __HIP_MEMORY_SCOPE_AGENT);
      __hip_atomic_store(gen, g + 1u, __ATOMIC_RELEASE, __HIP_MEMORY_SCOPE_AGENT);
    } else {
      while (__hip_atomic_load(gen, __ATOMIC_ACQUIRE, __HIP_MEMORY_SCOPE_AGENT) == g) {
        __builtin_amdgcn_s_sleep(1);
      }
    }
    __threadfence();
  }
  __syncthreads();
}

// ---------------- persistent main loop ----------------
// roles: 0 = G (gk = h@Z + bz), 1 = R (r = M@s -> jfn, logq), 2 = K (k = h@W2 + b2 -> kl, vfn)
__global__ __launch_bounds__(512) void ode_main(
    const float* __restrict__ x0, const float* __restrict__ b1,
    const float* __restrict__ wt, const float* __restrict__ W2,
    const float* __restrict__ b2, const float* __restrict__ mu,
    float* __restrict__ out,
    const float* __restrict__ Mm, const float* __restrict__ Zz,
    const float* __restrict__ cc, const float* __restrict__ bz,
    float* __restrict__ ux, float* __restrict__ xcur,
    float* __restrict__ gk, float* __restrict__ kvec,
    float* __restrict__ scal, unsigned* __restrict__ bar) {
  __shared__ float hv[Hn][4];        // h (G,K) or s (R), per (e, local sample)
  __shared__ float ubase[4][Hn];     // per-step u-base cache
  __shared__ float xbs[4][64];       // K: step-base x slice
  __shared__ float xis[4][64];       // K: stage x slice
  __shared__ float red2[8][16][17];  // wave partial sums
  __shared__ float sred[256][2];     // scalar-reduce scratch

  const int tid = threadIdx.x;
  const int wg = blockIdx.x;
  int role, cb, sh;
  if (wg < 32) { role = 0; cb = wg >> 1; sh = wg & 1; }
  else if (wg < 40) { role = 2; cb = (wg - 32) >> 1; sh = (wg - 32) & 1; }
  else { role = 1; cb = (wg - 40) >> 1; sh = (wg - 40) & 1; }
  const int c0 = cb * 64;
  const float* Mat = (role == 0) ? Zz : (role == 1) ? Mm : W2;
  const int ldm = (role == 2) ? Dn : Hn;

  for (int n = 0; n < 8; n++) {
    const int p = n & 1, pp = p ^ 1;
    for (int i = 0; i < 6; i++) {
      const float tstage = (float)n * DTf + cCc[i] * DTf;
      // ---- part 1: u -> h/s (redundant per WG, 4 samples x 1024) ----
      if (i == 0) {
        for (int idx = tid; idx < 4096; idx += 512) {
          const int e = idx & 1023, b4 = idx >> 10, b = sh * 4 + b4;
          float ub = ux[(pp * Bn + b) * Hn + e];
          #pragma unroll
          for (int j = 0; j < 6; j++)
            ub += DTf * cBW[j] * gk[((pp * 6 + j) * Bn + b) * Hn + e];
          ubase[b4][e] = ub;
          if (role == 0 && (unsigned)(e - c0) < 64u)
            ux[(p * Bn + b) * Hn + e] = ub;
          const float u = ub + b1[e] + wt[e] * tstage;
          const float h = tanhf(u);
          hv[e][b4] = (role == 1) ? (1.0f - h * h) : h;
        }
        if (role == 2) {
          for (int idx = tid; idx < 256; idx += 512) {
            const int b4 = idx >> 6, dl = idx & 63, b = sh * 4 + b4, d = c0 + dl;
            float xv = xcur[(pp * Bn + b) * Dn + d];
            #pragma unroll
            for (int j = 0; j < 6; j++)
              xv += DTf * cBW[j] * kvec[((pp * 6 + j) * Bn + b) * Dn + d];
            xbs[b4][dl] = xv;
            xis[b4][dl] = xv;
            xcur[(p * Bn + b) * Dn + d] = xv;
          }
        }
      } else {
        for (int idx = tid; idx < 4096; idx += 512) {
          const int e = idx & 1023, b4 = idx >> 10, b = sh * 4 + b4;
          float u = ubase[b4][e] + b1[e] + wt[e] * tstage;
          for (int j = 0; j < i; j++)
            u += DTf * cA[i][j] * gk[((p * 6 + j) * Bn + b) * Hn + e];
          const float h = tanhf(u);
          hv[e][b4] = (role == 1) ? (1.0f - h * h) : h;
        }
        if (role == 2) {
          for (int idx = tid; idx < 256; idx += 512) {
            const int b4 = idx >> 6, dl = idx & 63, b = sh * 4 + b4, d = c0 + dl;
            float xv = xbs[b4][dl];
            for (int j = 0; j < i; j++)
              xv += DTf * cA[i][j] * kvec[((p * 6 + j) * Bn + b) * Dn + d];
            xis[b4][dl] = xv;
          }
        }
      }
      __syncthreads();
      // ---- part 2: batched matvec (64 cols x 4 samples, K=1024) ----
      {
        const int cq = tid & 15, ks = tid >> 4;   // cq: col-quad, ks: K-segment
        const float* mp = Mat + (ks * 32) * ldm + (c0 + cq * 4);
        float acc[4][4] = {};
        #pragma unroll 4
        for (int l = 0; l < 32; l++) {
          const float4 mv = *(const float4*)mp;
          const float4 hb = *(const float4*)&hv[ks * 32 + l][0];
          const float mvv[4] = {mv.x, mv.y, mv.z, mv.w};
          const float hbv[4] = {hb.x, hb.y, hb.z, hb.w};
          #pragma unroll
          for (int c2 = 0; c2 < 4; c2++)
            #pragma unroll
            for (int b4 = 0; b4 < 4; b4++)
              acc[c2][b4] += mvv[c2] * hbv[b4];
          mp += ldm;
        }
        // intra-wave reduce over the wave's 4 K-segments
        #pragma unroll
        for (int c2 = 0; c2 < 4; c2++)
          #pragma unroll
          for (int b4 = 0; b4 < 4; b4++) {
            acc[c2][b4] += __shfl_xor(acc[c2][b4], 16, 64);
            acc[c2][b4] += __shfl_xor(acc[c2][b4], 32, 64);
          }
        if ((tid & 63) < 16) {
          const int w = tid >> 6;
          #pragma unroll
          for (int c2 = 0; c2 < 4; c2++)
            #pragma unroll
            for (int b4 = 0; b4 < 4; b4++)
              red2[w][cq][c2 * 4 + b4] = acc[c2][b4];
        }
      }
      __syncthreads();
      if (tid < 256) {
        const int co = tid >> 2, b4 = tid & 3, b = sh * 4 + b4;
        const int cq = co >> 2, c2 = co & 3;
        float s = 0.f;
        #pragma unroll
        for (int w = 0; w < 8; w++) s += red2[w][cq][c2 * 4 + b4];
        if (role == 0) {
          gk[((p * 6 + i) * Bn + b) * Hn + c0 + co] = s + bz[c0 + co];
        } else if (role == 1) {
          const float sv = hv[c0 + co][b4];
          sred[tid][0] = sv * s;            // s_k * (M s)_k  -> jfn
          sred[tid][1] = sv * cc[c0 + co];  // s_k * c_k      -> tr(J)
        } else {
          const float kv = s + b2[c0 + co];
          kvec[((p * 6 + i) * Bn + b) * Dn + c0 + co] = kv;
          const float xv = xis[b4][co];
          sred[tid][0] = (xv - mu[c0 + co]) * kv;  // dkl
          sred[tid][1] = kv * kv;                  // dvfn
        }
      }
      __syncthreads();
      if (role != 0 && tid < 4) {
        float s1 = 0.f, s2 = 0.f;
        for (int co = 0; co < 64; co++) {
          s1 += sred[co * 4 + tid][0];
          s2 += sred[co * 4 + tid][1];
        }
        const float wgt = DTf * cBW[i];
        const int b = sh * 4 + tid;
        if (role == 1) {
          atomicAdd(&scal[b * 4 + 3], wgt * s1);   // jfn
          atomicAdd(&scal[b * 4 + 0], -wgt * s2);  // dlogq = -tr(J)
        } else {
          atomicAdd(&scal[b * 4 + 1], wgt * s1);   // kl
          atomicAdd(&scal[b * 4 + 2], wgt * s2);   // vfn
        }
      }
      gridbar(bar, bar + 1);
    }
  }
  // ---- finalize: WGs 0..7 write output for sample b = wg ----
  if (wg < 8) {
    const int b = wg;
    for (int d = tid; d < Dn; d += 512) {
      float xv = xcur[(1 * Bn + b) * Dn + d];
      #pragma unroll
      for (int j = 0; j < 6; j++)
        xv += DTf * cBW[j] * kvec[((1 * 6 + j) * Bn + b) * Dn + d];
      out[b * 260 + d] = xv;
    }
    float ssum = 0.f;
    for (int d = tid; d < Dn; d += 512) {
      const float v = x0[b * Dn + d];
      ssum += v * v;
    }
    #pragma unroll
    for (int off = 32; off > 0; off >>= 1) ssum += __shfl_down(ssum, off, 64);
    if ((tid & 63) == 0) sred[tid >> 6][0] = ssum;
    __syncthreads();
    if (tid == 0) {
      float t = 0.f;
      for (int w = 0; w < 8; w++) t += sred[w][0];
      out[b * 260 + 256] = -0.5f * (470.49652900079245f + t) + scal[b * 4 + 0];
      out[b * 260 + 257] = scal[b * 4 + 1];
      out[b * 260 + 258] = scal[b * 4 + 2];
      out[b * 260 + 259] = scal[b * 4 + 3];
    }
  }
}

extern "C" void kernel_launch(void* const* d_in, const int* in_sizes, int n_in,
                              void* d_out, int out_size, void* d_ws, size_t ws_size,
                              hipStream_t stream) {
  (void)in_sizes; (void)n_in; (void)out_size; (void)ws_size;
  const float* x0 = (const float*)d_in[0];
  const float* W1 = (const float*)d_in[1];
  const float* b1 = (const float*)d_in[2];
  const float* wt = (const float*)d_in[3];
  const float* W2 = (const float*)d_in[4];
  const float* b2 = (const float*)d_in[5];
  const float* mu = (const float*)d_in[6];
  float* out = (float*)d_out;
  float* w = (float*)d_ws;

  float* Mm   = w;                 // 1048576
  float* Zz   = Mm + 1048576;      // 1048576
  float* cc   = Zz + 1048576;      // 1024
  float* bz   = cc + 1024;         // 1024
  float* ux   = bz + 1024;         // 2*8*1024
  float* xcur = ux + 16384;        // 2*8*256
  float* gk   = xcur + 4096;       // 2*6*8*1024
  float* kvec = gk + 98304;        // 2*6*8*256
  float* scal = kvec + 24576;      // 32
  unsigned* bar = (unsigned*)(scal + 32);

  precomp_M<<<dim3(256), dim3(256), 0, stream>>>(W1, W2, Mm);
  precomp_Z<<<dim3(256), dim3(256), 0, stream>>>(W1, W2, Zz);
  precomp_small<<<dim3(51), dim3(256), 0, stream>>>(x0, W1, W2, b2, cc, bz, ux,
                                                    xcur, gk, kvec, scal, bar);
  ode_main<<<dim3(NWG), dim3(512), 0, stream>>>(x0, b1, wt, W2, b2, mu, out, Mm,
                                                Zz, cc, bz, ux, xcur, gk, kvec,
                                                scal, bar);
}

// Round 2
// 851.530 us; speedup vs baseline: 1.0468x; 1.0468x over previous
//
#include <hip/hip_runtime.h>
#include <math.h>

#define Hn 1024
#define Dn 256
#define Bn 8
#define NSTAGE 48
#define DTf 0.125f

__constant__ float cA[6][5] = {
  {0.f,0.f,0.f,0.f,0.f},
  {1.0f/5.0f,0.f,0.f,0.f,0.f},
  {3.0f/40.0f, 9.0f/40.0f,0.f,0.f,0.f},
  {44.0f/45.0f, -56.0f/15.0f, 32.0f/9.0f,0.f,0.f},
  {19372.0f/6561.0f, -25360.0f/2187.0f, 64448.0f/6561.0f, -212.0f/729.0f,0.f},
  {9017.0f/3168.0f, -355.0f/33.0f, 46732.0f/5247.0f, 49.0f/176.0f, -5103.0f/18656.0f}
};
__constant__ float cCc[6] = {0.f, 0.2f, 0.3f, 0.8f, 8.0f/9.0f, 1.0f};
__constant__ float cBW[6] = {35.0f/384.0f, 0.f, 500.0f/1113.0f, 125.0f/192.0f,
                             -2187.0f/6784.0f, 11.0f/84.0f};

__device__ __forceinline__ float fast_tanh(float x) {
  const float ax = fabsf(x);
  const float z = __expf(-2.0f * ax);
  const float t = (1.0f - z) * __builtin_amdgcn_rcpf(1.0f + z);
  return copysignf(t, x);
}

// ---------------- merged precompute ----------------
// wg 0..255: M = (W1^T W1) .* (W2 W2^T); wg 256..511: Z = W2@W1;
// wg 512: zero scal/flags; wg 513..516: cc; wg 517..520: bz
__global__ __launch_bounds__(256) void precomp(
    const float* __restrict__ W1, const float* __restrict__ W2,
    const float* __restrict__ b2,
    float* __restrict__ Mm, float* __restrict__ Zz, float* __restrict__ cc,
    float* __restrict__ bz, float* __restrict__ scal, unsigned* __restrict__ flags) {
  __shared__ float sm[8704];
  const int tid = threadIdx.x;
  const int wg = blockIdx.x;
  if (wg < 256) {
    float* a1k  = sm;            // [32][64]
    float* a1l  = sm + 2048;     // [32][64]
    float* w2kT = sm + 4096;     // [32][72]
    float* w2lT = sm + 6400;     // [32][72]
    const int k0 = (wg & 15) * 64, l0 = (wg >> 4) * 64;
    const int kq = tid & 15, lq = tid >> 4;
    float g1[4][4] = {}, g2[4][4] = {};
    for (int dc = 0; dc < 8; dc++) {
      const int d0 = dc * 32;
      __syncthreads();
      for (int idx = tid; idx < 2048; idx += 256) {
        const int r1 = idx >> 6, c1 = idx & 63;
        a1k[r1 * 64 + c1] = W1[(d0 + r1) * Hn + k0 + c1];
        a1l[r1 * 64 + c1] = W1[(d0 + r1) * Hn + l0 + c1];
      }
      for (int idx = tid; idx < 2048; idx += 256) {
        const int r1 = idx >> 5, c1 = idx & 31;
        w2kT[c1 * 72 + r1] = W2[(k0 + r1) * Dn + d0 + c1];
        w2lT[c1 * 72 + r1] = W2[(l0 + r1) * Dn + d0 + c1];
      }
      __syncthreads();
      #pragma unroll 4
      for (int dd = 0; dd < 32; dd++) {
        const float4 ak = *(const float4*)&a1k[dd * 64 + kq * 4];
        const float4 al = *(const float4*)&a1l[dd * 64 + lq * 4];
        const float4 wk = *(const float4*)&w2kT[dd * 72 + kq * 4];
        const float4 wl = *(const float4*)&w2lT[dd * 72 + lq * 4];
        const float akv[4] = {ak.x, ak.y, ak.z, ak.w};
        const float alv[4] = {al.x, al.y, al.z, al.w};
        const float wkv[4] = {wk.x, wk.y, wk.z, wk.w};
        const float wlv[4] = {wl.x, wl.y, wl.z, wl.w};
        #pragma unroll
        for (int i = 0; i < 4; i++)
          #pragma unroll
          for (int j = 0; j < 4; j++) {
            g1[i][j] += akv[i] * alv[j];
            g2[i][j] += wkv[i] * wlv[j];
          }
      }
    }
    #pragma unroll
    for (int i = 0; i < 4; i++)
      #pragma unroll
      for (int j = 0; j < 4; j++)
        Mm[(k0 + kq * 4 + i) * Hn + l0 + lq * 4 + j] = g1[i][j] * g2[i][j];
  } else if (wg < 512) {
    float* w2lT = sm;            // [64][72]
    float* w1t  = sm + 4608;     // [64][64]
    const int bw = wg - 256;
    const int e0 = (bw & 15) * 64, l0 = (bw >> 4) * 64;
    const int eq = tid & 15, lq = tid >> 4;
    float acc[4][4] = {};
    for (int dc = 0; dc < 4; dc++) {
      const int d0 = dc * 64;
      __syncthreads();
      for (int idx = tid; idx < 4096; idx += 256) {
        const int r1 = idx >> 6, c1 = idx & 63;
        w2lT[c1 * 72 + r1] = W2[(l0 + r1) * Dn + d0 + c1];
        w1t[r1 * 64 + c1] = W1[(d0 + r1) * Hn + e0 + c1];
      }
      __syncthreads();
      #pragma unroll 4
      for (int dd = 0; dd < 64; dd++) {
        const float4 wv = *(const float4*)&w2lT[dd * 72 + lq * 4];
        const float4 xv = *(const float4*)&w1t[dd * 64 + eq * 4];
        const float wvv[4] = {wv.x, wv.y, wv.z, wv.w};
        const float xvv[4] = {xv.x, xv.y, xv.z, xv.w};
        #pragma unroll
        for (int i = 0; i < 4; i++)
          #pragma unroll
          for (int j = 0; j < 4; j++)
            acc[i][j] += wvv[i] * xvv[j];
      }
    }
    #pragma unroll
    for (int i = 0; i < 4; i++)
      #pragma unroll
      for (int j = 0; j < 4; j++)
        Zz[(l0 + lq * 4 + i) * Hn + e0 + eq * 4 + j] = acc[i][j];
  } else {
    const int w = wg - 512;
    if (w == 0) {
      if (tid < 64) scal[tid] = 0.f;
      if (tid < 33) flags[tid] = 0u;
    } else if (w < 5) {
      const int k = (w - 1) * 256 + tid;
      float s = 0.f;
      for (int d = 0; d < Dn; d++) s += W1[d * Hn + k] * W2[k * Dn + d];
      cc[k] = s;
    } else {
      const int e = (w - 5) * 256 + tid;
      float s = 0.f;
      for (int d = 0; d < Dn; d++) s += b2[d] * W1[d * Hn + e];
      bz[e] = s;
    }
  }
}

// ---------------- flag wait: min over 32 G-flags >= target ----------------
__device__ __forceinline__ void wait_flags(unsigned* flags, unsigned target) {
  if (threadIdx.x < 64) {
    const int l = threadIdx.x & 31;
    while (true) {
      const unsigned v = __hip_atomic_load(&flags[l], __ATOMIC_RELAXED,
                                           __HIP_MEMORY_SCOPE_AGENT);
      if (__all((int)(v >= target))) break;
      __builtin_amdgcn_s_sleep(1);
    }
  }
  __threadfence();   // acquire side
  __syncthreads();
}

// ---------------- persistent main ----------------
// wg 0..31:  G  (gk = h@Z + bz)         — the ONLY synchronized group
// wg 32..39: K  (k = h@W2 + b2 -> z, kl, vfn)   — poll-only consumer
// wg 40..71: R  (r = M@s -> jfn, trJ)            — poll-only consumer
__global__ __launch_bounds__(512) void ode_main(
    const float* __restrict__ x0, const float* __restrict__ W1,
    const float* __restrict__ b1, const float* __restrict__ wt,
    const float* __restrict__ W2, const float* __restrict__ b2,
    const float* __restrict__ mu, float* __restrict__ out,
    const float* __restrict__ Mm, const float* __restrict__ Zz,
    const float* __restrict__ cc, const float* __restrict__ bz,
    float* __restrict__ gk, float* __restrict__ scal,
    unsigned* __restrict__ flags) {
  __shared__ float hv[Hn][4];
  __shared__ float ubase[4][Hn];
  __shared__ float x0s[4][Dn];
  __shared__ float red2[8][16][17];
  __shared__ float sred[256][2];
  __shared__ float xbs[4][64];
  __shared__ float xis[4][64];
  __shared__ float klds[6][4][64];

  const int tid = threadIdx.x;
  const int wg = blockIdx.x;
  int role, cb, sh;
  if (wg < 32) { role = 0; cb = wg >> 1; sh = wg & 1; }
  else if (wg < 40) { role = 2; cb = (wg - 32) >> 1; sh = (wg - 32) & 1; }
  else { role = 1; cb = (wg - 40) >> 1; sh = (wg - 40) & 1; }
  const int c0 = cb * 64;
  const float* Mat = (role == 0) ? Zz : (role == 1) ? Mm : W2;
  const int ldm = (role == 2) ? Dn : Hn;

  // ---- prologue: x0 slice to LDS; ubase = x0 @ W1 (redundant per WG) ----
  for (int idx = tid; idx < 4 * Dn; idx += 512) {
    const int b4 = idx >> 8, d = idx & 255;
    x0s[b4][d] = x0[(sh * 4 + b4) * Dn + d];
  }
  __syncthreads();
  for (int e = tid; e < Hn; e += 512) {
    float a0 = 0.f, a1 = 0.f, a2 = 0.f, a3 = 0.f;
    for (int d = 0; d < Dn; d += 4) {
      const float4 xa = *(const float4*)&x0s[0][d];
      const float4 xb = *(const float4*)&x0s[1][d];
      const float4 xc = *(const float4*)&x0s[2][d];
      const float4 xd = *(const float4*)&x0s[3][d];
      const float w0 = W1[(d + 0) * Hn + e], w1 = W1[(d + 1) * Hn + e];
      const float w2 = W1[(d + 2) * Hn + e], w3 = W1[(d + 3) * Hn + e];
      a0 += xa.x * w0 + xa.y * w1 + xa.z * w2 + xa.w * w3;
      a1 += xb.x * w0 + xb.y * w1 + xb.z * w2 + xb.w * w3;
      a2 += xc.x * w0 + xc.y * w1 + xc.z * w2 + xc.w * w3;
      a3 += xd.x * w0 + xd.y * w1 + xd.z * w2 + xd.w * w3;
    }
    ubase[0][e] = a0; ubase[1][e] = a1; ubase[2][e] = a2; ubase[3][e] = a3;
  }
  if (role == 2) {
    // xbs init + x0^2 partial for log_q0
    if (tid < 256) {
      const int b4 = tid >> 6, dl = tid & 63;
      xbs[b4][dl] = x0s[b4][c0 + dl];
      const float v = x0s[b4][c0 + dl];
      sred[tid][0] = v * v;
    }
    __syncthreads();
    if (tid < 4) {
      float s = 0.f;
      for (int q = 0; q < 64; q++) s += sred[tid * 64 + q][0];
      atomicAdd(&scal[(sh * 4 + tid) * 8 + 4], s);
    }
  }

  float acc_a = 0.f, acc_b = 0.f;  // per-stage scalar accumulators (tid<4, R/K)

  for (int sidx = 0; sidx < NSTAGE; sidx++) {
    const int n = sidx / 6, i = sidx - n * 6;
    const float tstage = ((float)n + cCc[i]) * DTf;
    wait_flags(flags, (unsigned)sidx);   // all gk stages < sidx visible

    // ---- part 1: u -> h (G,K) / s=1-h^2 (R) ----
    if (i == 0) {
      for (int idx = tid; idx < 4096; idx += 512) {
        const int e = idx & 1023, b4 = idx >> 10, b = sh * 4 + b4;
        float ub = ubase[b4][e];
        if (n > 0) {
          const float* g = gk + (((n - 1) * 6) * Bn + b) * Hn + e;
          #pragma unroll
          for (int j = 0; j < 6; j++) ub += (DTf * cBW[j]) * g[j * Bn * Hn];
          ubase[b4][e] = ub;
        }
        const float h = fast_tanh(ub + b1[e] + wt[e] * tstage);
        hv[e][b4] = (role == 1) ? (1.0f - h * h) : h;
      }
      if (role == 2 && tid < 256) {
        const int b4 = tid >> 6, dl = tid & 63;
        float xv = xbs[b4][dl];
        if (n > 0) {
          #pragma unroll
          for (int j = 0; j < 6; j++) xv += (DTf * cBW[j]) * klds[j][b4][dl];
          xbs[b4][dl] = xv;
        }
        xis[b4][dl] = xv;
      }
    } else {
      for (int idx = tid; idx < 4096; idx += 512) {
        const int e = idx & 1023, b4 = idx >> 10, b = sh * 4 + b4;
        float u = ubase[b4][e] + b1[e] + wt[e] * tstage;
        const float* g = gk + ((n * 6) * Bn + b) * Hn + e;
        for (int j = 0; j < i; j++) u += (DTf * cA[i][j]) * g[j * Bn * Hn];
        const float h = fast_tanh(u);
        hv[e][b4] = (role == 1) ? (1.0f - h * h) : h;
      }
      if (role == 2 && tid < 256) {
        const int b4 = tid >> 6, dl = tid & 63;
        float xv = xbs[b4][dl];
        for (int j = 0; j < i; j++) xv += (DTf * cA[i][j]) * klds[j][b4][dl];
        xis[b4][dl] = xv;
      }
    }
    __syncthreads();

    // ---- part 2: batched matvec (64 cols x 4 samples, K=1024) ----
    {
      const int cq = tid & 15, ks = tid >> 4;
      const float* mp = Mat + (ks * 32) * ldm + (c0 + cq * 4);
      float acc[4][4] = {};
      #pragma unroll 4
      for (int l = 0; l < 32; l++) {
        const float4 mv = *(const float4*)mp;
        const float4 hb = *(const float4*)&hv[ks * 32 + l][0];
        const float mvv[4] = {mv.x, mv.y, mv.z, mv.w};
        const float hbv[4] = {hb.x, hb.y, hb.z, hb.w};
        #pragma unroll
        for (int c2 = 0; c2 < 4; c2++)
          #pragma unroll
          for (int b4 = 0; b4 < 4; b4++)
            acc[c2][b4] += mvv[c2] * hbv[b4];
        mp += ldm;
      }
      #pragma unroll
      for (int c2 = 0; c2 < 4; c2++)
        #pragma unroll
        for (int b4 = 0; b4 < 4; b4++) {
          acc[c2][b4] += __shfl_xor(acc[c2][b4], 16, 64);
          acc[c2][b4] += __shfl_xor(acc[c2][b4], 32, 64);
        }
      if ((tid & 63) < 16) {
        const int w = tid >> 6;
        #pragma unroll
        for (int c2 = 0; c2 < 4; c2++)
          #pragma unroll
          for (int b4 = 0; b4 < 4; b4++)
            red2[w][cq][c2 * 4 + b4] = acc[c2][b4];
      }
    }
    __syncthreads();

    // ---- consume per role ----
    if (tid < 256) {
      const int co = tid >> 2, b4 = tid & 3, b = sh * 4 + b4;
      const int cq = co >> 2, c2 = co & 3;
      float s = 0.f;
      #pragma unroll
      for (int w = 0; w < 8; w++) s += red2[w][cq][c2 * 4 + b4];
      if (role == 0) {
        gk[(sidx * Bn + b) * Hn + c0 + co] = s + bz[c0 + co];
      } else if (role == 1) {
        const float sv = hv[c0 + co][b4];
        sred[tid][0] = sv * s;            // -> jfn
        sred[tid][1] = sv * cc[c0 + co];  // -> tr(J)
      } else {
        const float kv = s + b2[c0 + co];
        klds[i][b4][co] = kv;
        const float xv = xis[b4][co];
        sred[tid][0] = (xv - mu[c0 + co]) * kv;  // -> kl
        sred[tid][1] = kv * kv;                  // -> vfn
      }
    }
    if (role == 0) {
      __syncthreads();  // gk slice fully written
      if (tid == 0) {
        __threadfence();
        __hip_atomic_store(&flags[wg], (unsigned)(sidx + 1), __ATOMIC_RELEASE,
                           __HIP_MEMORY_SCOPE_AGENT);
      }
    } else {
      __syncthreads();
      if (tid < 4) {
        float s1 = 0.f, s2 = 0.f;
        for (int q = 0; q < 64; q++) {
          s1 += sred[q * 4 + tid][0];
          s2 += sred[q * 4 + tid][1];
        }
        const float wgt = DTf * cBW[i];
        if (role == 1) { acc_a += -wgt * s2; acc_b += wgt * s1; }  // trJ, jfn
        else           { acc_a += wgt * s1;  acc_b += wgt * s2; }  // kl, vfn
      }
    }
  }

  // ---- finalize ----
  if (role == 1) {
    if (tid < 4) {
      const int b = sh * 4 + tid;
      atomicAdd(&scal[b * 8 + 0], acc_a);  // trJ (signed)
      atomicAdd(&scal[b * 8 + 3], acc_b);  // jfn
    }
  } else if (role == 2) {
    __syncthreads();  // klds stage-5 writes visible
    if (tid < 256) {
      const int b4 = tid >> 6, dl = tid & 63;
      float xv = xbs[b4][dl];
      #pragma unroll
      for (int j = 0; j < 6; j++) xv += (DTf * cBW[j]) * klds[j][b4][dl];
      out[(sh * 4 + b4) * 260 + c0 + dl] = xv;
    }
    if (tid < 4) {
      const int b = sh * 4 + tid;
      atomicAdd(&scal[b * 8 + 1], acc_a);  // kl
      atomicAdd(&scal[b * 8 + 2], acc_b);  // vfn
    }
  }
  if (role != 0) {
    __syncthreads();
    if (tid == 0) {
      __threadfence();
      const unsigned old = __hip_atomic_fetch_add(&flags[32], 1u, __ATOMIC_ACQ_REL,
                                                  __HIP_MEMORY_SCOPE_AGENT);
      if (old == 39u) {  // last of the 40 consumers writes scalars
        for (int b = 0; b < Bn; b++) {
          const float trj = __hip_atomic_load(&scal[b * 8 + 0], __ATOMIC_RELAXED, __HIP_MEMORY_SCOPE_AGENT);
          const float kl  = __hip_atomic_load(&scal[b * 8 + 1], __ATOMIC_RELAXED, __HIP_MEMORY_SCOPE_AGENT);
          const float vfn = __hip_atomic_load(&scal[b * 8 + 2], __ATOMIC_RELAXED, __HIP_MEMORY_SCOPE_AGENT);
          const float jfn = __hip_atomic_load(&scal[b * 8 + 3], __ATOMIC_RELAXED, __HIP_MEMORY_SCOPE_AGENT);
          const float xsq = __hip_atomic_load(&scal[b * 8 + 4], __ATOMIC_RELAXED, __HIP_MEMORY_SCOPE_AGENT);
          out[b * 260 + 256] = -0.5f * (470.49652900079245f + xsq) + trj;
          out[b * 260 + 257] = kl;
          out[b * 260 + 258] = vfn;
          out[b * 260 + 259] = jfn;
        }
      }
    }
  }
}

extern "C" void kernel_launch(void* const* d_in, const int* in_sizes, int n_in,
                              void* d_out, int out_size, void* d_ws, size_t ws_size,
                              hipStream_t stream) {
  (void)in_sizes; (void)n_in; (void)out_size; (void)ws_size;
  const float* x0 = (const float*)d_in[0];
  const float* W1 = (const float*)d_in[1];
  const float* b1 = (const float*)d_in[2];
  const float* wt = (const float*)d_in[3];
  const float* W2 = (const float*)d_in[4];
  const float* b2 = (const float*)d_in[5];
  const float* mu = (const float*)d_in[6];
  float* out = (float*)d_out;
  float* w = (float*)d_ws;

  float* Mm   = w;                  // 1048576
  float* Zz   = Mm + 1048576;       // 1048576
  float* cc   = Zz + 1048576;       // 1024
  float* bz   = cc + 1024;          // 1024
  float* gk   = bz + 1024;          // 48*8*1024 = 393216
  float* scal = gk + 393216;        // 64 (8 samples x 8 slots)
  unsigned* flags = (unsigned*)(scal + 64);  // 32 G-flags + 1 done counter

  precomp<<<dim3(521), dim3(256), 0, stream>>>(W1, W2, b2, Mm, Zz, cc, bz, scal, flags);
  ode_main<<<dim3(72), dim3(512), 0, stream>>>(x0, W1, b1, wt, W2, b2, mu, out,
                                               Mm, Zz, cc, bz, gk, scal, flags);
}

// Round 3
// 339.722 us; speedup vs baseline: 2.6239x; 2.5066x over previous
//
#include <hip/hip_runtime.h>
#include <math.h>

#define Hn 1024
#define Dn 256
#define Bn 8
#define DTf 0.125f

constexpr float kA[6][5] = {
  {0.f, 0.f, 0.f, 0.f, 0.f},
  {1.0f/5.0f, 0.f, 0.f, 0.f, 0.f},
  {3.0f/40.0f, 9.0f/40.0f, 0.f, 0.f, 0.f},
  {44.0f/45.0f, -56.0f/15.0f, 32.0f/9.0f, 0.f, 0.f},
  {19372.0f/6561.0f, -25360.0f/2187.0f, 64448.0f/6561.0f, -212.0f/729.0f, 0.f},
  {9017.0f/3168.0f, -355.0f/33.0f, 46732.0f/5247.0f, 49.0f/176.0f, -5103.0f/18656.0f}
};
constexpr float kC[6] = {0.f, 0.2f, 0.3f, 0.8f, 8.0f/9.0f, 1.0f};
constexpr float kBW[6] = {35.0f/384.0f, 0.f, 500.0f/1113.0f, 125.0f/192.0f,
                          -2187.0f/6784.0f, 11.0f/84.0f};

__device__ __forceinline__ float fast_tanh(float x) {
  const float ax = fabsf(x);
  const float z = __expf(-2.0f * ax);
  const float t = (1.0f - z) * __builtin_amdgcn_rcpf(1.0f + z);
  return copysignf(t, x);
}

// ---------------- merged precompute (unchanged from round 2) ----------------
__global__ __launch_bounds__(256) void precomp(
    const float* __restrict__ W1, const float* __restrict__ W2,
    const float* __restrict__ b2,
    float* __restrict__ Mm, float* __restrict__ Zz, float* __restrict__ cc,
    float* __restrict__ bz, float* __restrict__ scal, unsigned* __restrict__ flags) {
  __shared__ float sm[8704];
  const int tid = threadIdx.x;
  const int wg = blockIdx.x;
  if (wg < 256) {
    float* a1k  = sm;            // [32][64]
    float* a1l  = sm + 2048;     // [32][64]
    float* w2kT = sm + 4096;     // [32][72]
    float* w2lT = sm + 6400;     // [32][72]
    const int k0 = (wg & 15) * 64, l0 = (wg >> 4) * 64;
    const int kq = tid & 15, lq = tid >> 4;
    float g1[4][4] = {}, g2[4][4] = {};
    for (int dc = 0; dc < 8; dc++) {
      const int d0 = dc * 32;
      __syncthreads();
      for (int idx = tid; idx < 2048; idx += 256) {
        const int r1 = idx >> 6, c1 = idx & 63;
        a1k[r1 * 64 + c1] = W1[(d0 + r1) * Hn + k0 + c1];
        a1l[r1 * 64 + c1] = W1[(d0 + r1) * Hn + l0 + c1];
      }
      for (int idx = tid; idx < 2048; idx += 256) {
        const int r1 = idx >> 5, c1 = idx & 31;
        w2kT[c1 * 72 + r1] = W2[(k0 + r1) * Dn + d0 + c1];
        w2lT[c1 * 72 + r1] = W2[(l0 + r1) * Dn + d0 + c1];
      }
      __syncthreads();
      #pragma unroll 4
      for (int dd = 0; dd < 32; dd++) {
        const float4 ak = *(const float4*)&a1k[dd * 64 + kq * 4];
        const float4 al = *(const float4*)&a1l[dd * 64 + lq * 4];
        const float4 wk = *(const float4*)&w2kT[dd * 72 + kq * 4];
        const float4 wl = *(const float4*)&w2lT[dd * 72 + lq * 4];
        const float akv[4] = {ak.x, ak.y, ak.z, ak.w};
        const float alv[4] = {al.x, al.y, al.z, al.w};
        const float wkv[4] = {wk.x, wk.y, wk.z, wk.w};
        const float wlv[4] = {wl.x, wl.y, wl.z, wl.w};
        #pragma unroll
        for (int i = 0; i < 4; i++)
          #pragma unroll
          for (int j = 0; j < 4; j++) {
            g1[i][j] += akv[i] * alv[j];
            g2[i][j] += wkv[i] * wlv[j];
          }
      }
    }
    #pragma unroll
    for (int i = 0; i < 4; i++)
      #pragma unroll
      for (int j = 0; j < 4; j++)
        Mm[(k0 + kq * 4 + i) * Hn + l0 + lq * 4 + j] = g1[i][j] * g2[i][j];
  } else if (wg < 512) {
    float* w2lT = sm;            // [64][72]
    float* w1t  = sm + 4608;     // [64][64]
    const int bw = wg - 256;
    const int e0 = (bw & 15) * 64, l0 = (bw >> 4) * 64;
    const int eq = tid & 15, lq = tid >> 4;
    float acc[4][4] = {};
    for (int dc = 0; dc < 4; dc++) {
      const int d0 = dc * 64;
      __syncthreads();
      for (int idx = tid; idx < 4096; idx += 256) {
        const int r1 = idx >> 6, c1 = idx & 63;
        w2lT[c1 * 72 + r1] = W2[(l0 + r1) * Dn + d0 + c1];
        w1t[r1 * 64 + c1] = W1[(d0 + r1) * Hn + e0 + c1];
      }
      __syncthreads();
      #pragma unroll 4
      for (int dd = 0; dd < 64; dd++) {
        const float4 wv = *(const float4*)&w2lT[dd * 72 + lq * 4];
        const float4 xv = *(const float4*)&w1t[dd * 64 + eq * 4];
        const float wvv[4] = {wv.x, wv.y, wv.z, wv.w};
        const float xvv[4] = {xv.x, xv.y, xv.z, xv.w};
        #pragma unroll
        for (int i = 0; i < 4; i++)
          #pragma unroll
          for (int j = 0; j < 4; j++)
            acc[i][j] += wvv[i] * xvv[j];
      }
    }
    #pragma unroll
    for (int i = 0; i < 4; i++)
      #pragma unroll
      for (int j = 0; j < 4; j++)
        Zz[(l0 + lq * 4 + i) * Hn + e0 + eq * 4 + j] = acc[i][j];
  } else {
    const int w = wg - 512;
    if (w == 0) {
      if (tid < 64) scal[tid] = 0.f;
      if (tid < 33) flags[tid] = 0u;
    } else if (w < 5) {
      const int k = (w - 1) * 256 + tid;
      float s = 0.f;
      for (int d = 0; d < Dn; d++) s += W1[d * Hn + k] * W2[k * Dn + d];
      cc[k] = s;
    } else {
      const int e = (w - 5) * 256 + tid;
      float s = 0.f;
      for (int d = 0; d < Dn; d++) s += b2[d] * W1[d * Hn + e];
      bz[e] = s;
    }
  }
}

// ---------------- fence-free flag wait (relaxed sc1 loads, no buffer_inv) ----
__device__ __forceinline__ void wait_half(unsigned* f16, unsigned target) {
  if (threadIdx.x < 64) {
    unsigned v;
    do {
      v = __hip_atomic_load(&f16[threadIdx.x & 15], __ATOMIC_RELAXED,
                            __HIP_MEMORY_SCOPE_AGENT);
    } while (__any((int)(v < target)));
  }
  __syncthreads();
  __builtin_amdgcn_sched_barrier(0);  // keep h loads from hoisting above the wait
}

// ---------------- persistent main ----------------
// wg 0..31:  G  (produces h; the ONLY synchronized group; gk history in regs)
// wg 32..39: K  (k = h@W2 + b2 -> z, kl, vfn; k history in regs)
// wg 40..71: R  (r = M@s, s = 1-h^2 -> jfn, trJ)
__global__ __launch_bounds__(512) void ode_main(
    const float* __restrict__ x0, const float* __restrict__ W1,
    const float* __restrict__ b1, const float* __restrict__ wt,
    const float* __restrict__ W2g, const float* __restrict__ b2,
    const float* __restrict__ mu, float* __restrict__ out,
    const float* __restrict__ Mm, const float* __restrict__ Zz,
    const float* __restrict__ cc, const float* __restrict__ bz,
    float* __restrict__ hbuf, float* __restrict__ scal,
    unsigned* __restrict__ flags) {
  __shared__ float hv[Hn][4];        // 16 KB: h (G,K) or s=1-h^2 (R)
  __shared__ float red2[8][16][17];  // 8.7 KB
  __shared__ float sred[256][2];     // 2 KB
  __shared__ float x0g[4][260];      // 4 KB (G prologue only)

  const int tid = threadIdx.x;
  const int wg = blockIdx.x;
  int role, cb, sh;
  if (wg < 32) { role = 0; cb = wg >> 1; sh = wg & 1; }
  else if (wg < 40) { role = 2; cb = (wg - 32) >> 1; sh = (wg - 32) & 1; }
  else { role = 1; cb = (wg - 40) >> 1; sh = (wg - 40) & 1; }
  const int c0 = cb * 64;
  unsigned* f16 = flags + sh * 16;
  const int co = tid >> 2, b4 = tid & 3, bglob = sh * 4 + b4;

  float ubr = 0.f, xbr = 0.f;
  float gkr[6] = {}, kr[6] = {};
  float b1c = 0.f, wtc = 0.f, bzc = 0.f, ccr = 0.f, b2c = 0.f, muc = 0.f;

  // ---- prologue ----
  if (role == 0) {
    for (int idx = tid; idx < 1024; idx += 512)
      x0g[idx >> 8][idx & 255] = x0[(sh * 4 + (idx >> 8)) * Dn + (idx & 255)];
    __syncthreads();
    if (tid < 256) {
      const int col = c0 + co;
      b1c = b1[col]; wtc = wt[col]; bzc = bz[col];
      float ub = 0.f;
      for (int d = 0; d < Dn; ++d) ub += x0g[b4][d] * W1[d * Hn + col];
      ubr = ub;
      const float h0 = fast_tanh(ubr + b1c);   // t=0
      __hip_atomic_store(&hbuf[(0 * Bn + bglob) * Hn + col], h0,
                         __ATOMIC_RELAXED, __HIP_MEMORY_SCOPE_AGENT);
    }
    __builtin_amdgcn_s_waitcnt(0);
    __syncthreads();
    if (tid == 0)
      __hip_atomic_store(&f16[cb], 1u, __ATOMIC_RELAXED, __HIP_MEMORY_SCOPE_AGENT);
  } else if (role == 2) {
    if (tid < 256) {
      const int d = c0 + co;
      xbr = x0[bglob * Dn + d];
      muc = mu[d]; b2c = b2[d];
      sred[tid][0] = xbr * xbr;
    }
    __syncthreads();
    if (tid < 4) {
      float s = 0.f;
      for (int q = 0; q < 64; ++q) s += sred[q * 4 + tid][0];
      atomicAdd(&scal[(sh * 4 + tid) * 8 + 4], s);   // sum x0^2 for log_q0
    }
  } else {
    if (tid < 256) ccr = cc[c0 + co];
  }

  const float* Mat = (role == 0) ? Zz : (role == 1) ? Mm : W2g;
  const int ldm = (role == 2) ? Dn : Hn;
  float acc_a = 0.f, acc_b = 0.f;

  for (int n = 0; n < 8; ++n) {
    #pragma unroll
    for (int i = 0; i < 6; ++i) {
      if (role == 1 && i == 1) continue;   // BW[1]==0: R output unused
      const int s = n * 6 + i;
      if (role == 2 && i == 0 && n > 0 && tid < 256)
        xbr += DTf * (kBW[0] * kr[0] + kBW[2] * kr[2] + kBW[3] * kr[3] +
                      kBW[4] * kr[4] + kBW[5] * kr[5]);

      wait_half(f16, (unsigned)(s + 1));

      // ---- load h_s (plain float4; write-once-before-read makes this safe) ----
      for (int idx = tid; idx < 1024; idx += 512) {
        const int bb = idx >> 8, e4 = (idx & 255) * 4;
        const float4 hval =
            *(const float4*)&hbuf[((size_t)s * Bn + sh * 4 + bb) * Hn + e4];
        if (role == 1) {
          hv[e4 + 0][bb] = 1.f - hval.x * hval.x;
          hv[e4 + 1][bb] = 1.f - hval.y * hval.y;
          hv[e4 + 2][bb] = 1.f - hval.z * hval.z;
          hv[e4 + 3][bb] = 1.f - hval.w * hval.w;
        } else {
          hv[e4 + 0][bb] = hval.x; hv[e4 + 1][bb] = hval.y;
          hv[e4 + 2][bb] = hval.z; hv[e4 + 3][bb] = hval.w;
        }
      }
      __syncthreads();

      // ---- matvec: 64 cols x 4 samples, K=1024 (Mat hot in L2) ----
      {
        const int cq = tid & 15, ks = tid >> 4;
        const float* mp = Mat + (ks * 32) * ldm + (c0 + cq * 4);
        float acc[4][4] = {};
        #pragma unroll 4
        for (int l = 0; l < 32; ++l) {
          const float4 mv = *(const float4*)mp;
          const float4 hb = *(const float4*)&hv[ks * 32 + l][0];
          const float mvv[4] = {mv.x, mv.y, mv.z, mv.w};
          const float hbv[4] = {hb.x, hb.y, hb.z, hb.w};
          #pragma unroll
          for (int c2 = 0; c2 < 4; c2++)
            #pragma unroll
            for (int bb = 0; bb < 4; bb++)
              acc[c2][bb] += mvv[c2] * hbv[bb];
          mp += ldm;
        }
        #pragma unroll
        for (int c2 = 0; c2 < 4; c2++)
          #pragma unroll
          for (int bb = 0; bb < 4; bb++) {
            acc[c2][bb] += __shfl_xor(acc[c2][bb], 16, 64);
            acc[c2][bb] += __shfl_xor(acc[c2][bb], 32, 64);
          }
        if ((tid & 63) < 16) {
          const int w = tid >> 6;
          #pragma unroll
          for (int c2 = 0; c2 < 4; c2++)
            #pragma unroll
            for (int bb = 0; bb < 4; bb++)
              red2[w][cq][c2 * 4 + bb] = acc[c2][bb];
        }
      }
      __syncthreads();

      // ---- per-role epilogue ----
      if (tid < 256) {
        const int cq2 = co >> 2, c2 = co & 3;
        float r = 0.f;
        #pragma unroll
        for (int w = 0; w < 8; ++w) r += red2[w][cq2][c2 * 4 + b4];
        if (role == 0) {
          gkr[i] = r + bzc;
          if (s < 47) {
            float u;
            if (i == 5) {
              ubr += DTf * (kBW[0] * gkr[0] + kBW[2] * gkr[2] + kBW[3] * gkr[3] +
                            kBW[4] * gkr[4] + kBW[5] * gkr[5]);
              u = ubr + b1c + wtc * ((float)(n + 1) * DTf);
            } else {
              u = ubr + b1c + wtc * (((float)n + kC[i + 1]) * DTf);
              #pragma unroll
              for (int j = 0; j <= i; ++j) u += DTf * kA[i + 1][j] * gkr[j];
            }
            const float hn = fast_tanh(u);
            __hip_atomic_store(&hbuf[((size_t)(s + 1) * Bn + bglob) * Hn + c0 + co],
                               hn, __ATOMIC_RELAXED, __HIP_MEMORY_SCOPE_AGENT);
          }
        } else if (role == 1) {
          const float sv = hv[c0 + co][b4];
          sred[tid][0] = sv * r;            // -> jfn
          sred[tid][1] = sv * ccr;          // -> tr(J)
        } else {
          const float kv = r + b2c;
          kr[i] = kv;
          float xi = xbr;
          #pragma unroll
          for (int j = 0; j < i; ++j) xi += DTf * kA[i][j] * kr[j];
          sred[tid][0] = (xi - muc) * kv;   // -> kl
          sred[tid][1] = kv * kv;           // -> vfn
        }
      }
      if (role == 0) {
        __builtin_amdgcn_s_waitcnt(0);
        __syncthreads();   // all h stores of this WG drained (vmcnt(0) pre-barrier)
        if (tid == 0 && s < 47)
          __hip_atomic_store(&f16[cb], (unsigned)(s + 2), __ATOMIC_RELAXED,
                             __HIP_MEMORY_SCOPE_AGENT);
      } else {
        __syncthreads();
        if (tid < 4) {
          float s1 = 0.f, s2 = 0.f;
          for (int q = 0; q < 64; ++q) {
            s1 += sred[q * 4 + tid][0];
            s2 += sred[q * 4 + tid][1];
          }
          const float wgt = DTf * kBW[i];
          if (role == 1) { acc_a += -wgt * s2; acc_b += wgt * s1; }  // trJ, jfn
          else           { acc_a +=  wgt * s1; acc_b += wgt * s2; }  // kl, vfn
        }
      }
    }
  }

  // ---- finalize ----
  if (role == 1) {
    if (tid < 4) {
      atomicAdd(&scal[(sh * 4 + tid) * 8 + 0], acc_a);
      atomicAdd(&scal[(sh * 4 + tid) * 8 + 3], acc_b);
    }
  } else if (role == 2) {
    if (tid < 256) {
      const float z = xbr + DTf * (kBW[0] * kr[0] + kBW[2] * kr[2] +
                                   kBW[3] * kr[3] + kBW[4] * kr[4] +
                                   kBW[5] * kr[5]);
      out[bglob * 260 + c0 + co] = z;
    }
    if (tid < 4) {
      atomicAdd(&scal[(sh * 4 + tid) * 8 + 1], acc_a);
      atomicAdd(&scal[(sh * 4 + tid) * 8 + 2], acc_b);
    }
  }
  if (role != 0) {
    __syncthreads();
    if (tid == 0) {
      __builtin_amdgcn_s_waitcnt(0);
      const unsigned old = __hip_atomic_fetch_add(&flags[32], 1u, __ATOMIC_RELAXED,
                                                  __HIP_MEMORY_SCOPE_AGENT);
      if (old == 39u) {  // last of the 40 consumers writes scalars
        for (int b = 0; b < Bn; ++b) {
          const float trj = __hip_atomic_load(&scal[b * 8 + 0], __ATOMIC_RELAXED, __HIP_MEMORY_SCOPE_AGENT);
          const float kl  = __hip_atomic_load(&scal[b * 8 + 1], __ATOMIC_RELAXED, __HIP_MEMORY_SCOPE_AGENT);
          const float vfn = __hip_atomic_load(&scal[b * 8 + 2], __ATOMIC_RELAXED, __HIP_MEMORY_SCOPE_AGENT);
          const float jfn = __hip_atomic_load(&scal[b * 8 + 3], __ATOMIC_RELAXED, __HIP_MEMORY_SCOPE_AGENT);
          const float xsq = __hip_atomic_load(&scal[b * 8 + 4], __ATOMIC_RELAXED, __HIP_MEMORY_SCOPE_AGENT);
          out[b * 260 + 256] = -0.5f * (470.49652900079245f + xsq) + trj;
          out[b * 260 + 257] = kl;
          out[b * 260 + 258] = vfn;
          out[b * 260 + 259] = jfn;
        }
      }
    }
  }
}

extern "C" void kernel_launch(void* const* d_in, const int* in_sizes, int n_in,
                              void* d_out, int out_size, void* d_ws, size_t ws_size,
                              hipStream_t stream) {
  (void)in_sizes; (void)n_in; (void)out_size; (void)ws_size;
  const float* x0 = (const float*)d_in[0];
  const float* W1 = (const float*)d_in[1];
  const float* b1 = (const float*)d_in[2];
  const float* wt = (const float*)d_in[3];
  const float* W2 = (const float*)d_in[4];
  const float* b2 = (const float*)d_in[5];
  const float* mu = (const float*)d_in[6];
  float* out = (float*)d_out;
  float* w = (float*)d_ws;

  float* Mm   = w;                  // 1048576
  float* Zz   = Mm + 1048576;       // 1048576
  float* cc   = Zz + 1048576;       // 1024
  float* bz   = cc + 1024;          // 1024
  float* hbuf = bz + 1024;          // 48*8*1024 = 393216
  float* scal = hbuf + 393216;      // 64 (8 samples x 8 slots)
  unsigned* flags = (unsigned*)(scal + 64);  // 32 G-flags + 1 done counter

  precomp<<<dim3(521), dim3(256), 0, stream>>>(W1, W2, b2, Mm, Zz, cc, bz, scal, flags);
  ode_main<<<dim3(72), dim3(512), 0, stream>>>(x0, W1, b1, wt, W2, b2, mu, out,
                                               Mm, Zz, cc, bz, hbuf, scal, flags);
}